// Round 5
// baseline (459.720 us; speedup 1.0000x reference)
//
#include <hip/hip_runtime.h>
#include <math.h>

#define NROW 16384   // B*N rows
#define NCOL 4096
#define CDIM 256
#define DKDIM 64
#define SCALE 0.125f // DK^-0.5

typedef float v4f __attribute__((ext_vector_type(4)));
typedef __attribute__((ext_vector_type(8))) short short8v;  // 8 bf16 = 4 VGPR
typedef __attribute__((ext_vector_type(4))) float f32x4;

// ---- monotone float<->u32 key helpers (unsigned compare == float compare) ----
__device__ __forceinline__ unsigned mono(float v) {
  unsigned u = __float_as_uint(v);
  unsigned s = (unsigned)(((int)u) >> 31);
  return u ^ (s | 0x80000000u);
}
__device__ __forceinline__ float unmono(unsigned k) {
  unsigned u = (k & 0x80000000u) ? (k ^ 0x80000000u) : ~k;
  return __uint_as_float(u);
}
__device__ __forceinline__ unsigned short f2bf(float f) {  // RNE bf16
  unsigned u = __float_as_uint(f);
  u += 0x7FFFu + ((u >> 16) & 1u);
  return (unsigned short)(u >> 16);
}
__device__ __forceinline__ unsigned umaxu(unsigned a, unsigned b) { return a > b ? a : b; }

// ---- top-8 maintenance on packed keys (proven group-of-8 insert logic) ----
__device__ __forceinline__ void ins8(unsigned tk[8], unsigned& tmin, int& tmpos, unsigned v) {
  #pragma unroll
  for (int j = 0; j < 8; ++j) if (j == tmpos) tk[j] = v;
  tmin = tk[0]; tmpos = 0;
  #pragma unroll
  for (int j = 1; j < 8; ++j) if (tk[j] < tmin) { tmin = tk[j]; tmpos = j; }
}
__device__ __forceinline__ unsigned umax8(const unsigned kv[8]) {
  unsigned a = umaxu(umaxu(kv[0], kv[1]), umaxu(kv[2], kv[3]));
  unsigned b = umaxu(umaxu(kv[4], kv[5]), umaxu(kv[6], kv[7]));
  return umaxu(a, b);
}
__device__ __forceinline__ void seed8r(const unsigned kv[8],
                                       unsigned tk[8], unsigned& tmin, int& tmpos) {
  #pragma unroll
  for (int j = 0; j < 8; ++j) tk[j] = kv[j];
  tmin = tk[0]; tmpos = 0;
  #pragma unroll
  for (int j = 1; j < 8; ++j) if (tk[j] < tmin) { tmin = tk[j]; tmpos = j; }
}
__device__ __forceinline__ void scan8r(const unsigned kvin[8],
                                       unsigned tk[8], unsigned& tmin, int& tmpos) {
  unsigned kv[8];
  #pragma unroll
  for (int j = 0; j < 8; ++j) kv[j] = kvin[j];
  unsigned gm = umax8(kv);
  #pragma unroll
  for (int pass = 0; pass < 2; ++pass) {
    if (__any(gm > tmin)) {            // wave-uniform branch
      if (gm > tmin) {                 // per-lane insert (keys unique: col in low bits)
        ins8(tk, tmin, tmpos, gm);
        #pragma unroll
        for (int j = 0; j < 8; ++j) if (kv[j] == gm) kv[j] = 0u;
      }
      gm = umax8(kv);
    }
  }
  if (__any(gm > tmin)) {              // rare: >=3 qualifiers in this group
    #pragma unroll
    for (int j = 0; j < 8; ++j) if (kv[j] > tmin) ins8(tk, tmin, tmpos, kv[j]);
  }
}

// LDS key array XOR swizzle (u32 granularity, keeps uint4 alignment):
// spreads the s*64 read stride across bank groups; bijective within each
// 64-u32 block (XOR touches bits 2-4 only, off>>6 untouched).
__device__ __forceinline__ int kswz(int row, int off) {
  return row * 512 + (off ^ (((off >> 6) & 7) << 2));
}
__device__ __forceinline__ void ld8swz(const unsigned* k, int row, int off,
                                       unsigned kv[8]) {
  uint4 ka = *(const uint4*)&k[kswz(row, off)];
  uint4 kb = *(const uint4*)&k[kswz(row, off + 4)];
  kv[0] = ka.x; kv[1] = ka.y; kv[2] = ka.z; kv[3] = ka.w;
  kv[4] = kb.x; kv[5] = kb.y; kv[6] = kb.z; kv[7] = kb.w;
}

// ---------------- Kernel 1: fused Q/K projection (fp32 + bf16 row-major) ----
__global__ __launch_bounds__(512, 2) void qk_proj(
    const float* __restrict__ x, const float* __restrict__ Wq,
    const float* __restrict__ Wk, float* __restrict__ Qt,
    float* __restrict__ Kt, unsigned short* __restrict__ Qh,
    unsigned short* __restrict__ Kh) {
  __shared__ float4 xs4[64][65];  // row stride 65 f4-units -> bank-group spread
  const int t = threadIdx.x;
  const int rb = blockIdx.x;      // 256 blocks of 64 rows
  {
    const float4* xg = (const float4*)(x + (size_t)rb * 64 * CDIM);
    #pragma unroll
    for (int i = 0; i < 8; ++i) {
      int idx = i * 512 + t;      // 0..4095
      xs4[idx >> 6][idx & 63] = xg[idx];
    }
  }
  __syncthreads();

  const int lane = t & 63;
  const int wu = __builtin_amdgcn_readfirstlane(t >> 6);  // wave id, uniform
  const int proj = wu >> 2;
  const int chunk = wu & 3;       // d-chunk: d = chunk*16 .. +15
  const float* __restrict__ Wp = proj ? Wk : Wq;

  float acc[16];
  #pragma unroll
  for (int j = 0; j < 16; ++j) acc[j] = 0.f;

  #pragma unroll 4
  for (int cs = 0; cs < 64; ++cs) {        // 4 c's per step
    float4 xv = xs4[lane][cs];
    const float xc[4] = {xv.x, xv.y, xv.z, xv.w};
    #pragma unroll
    for (int i = 0; i < 4; ++i) {
      const float4* __restrict__ w4 =
          (const float4*)(Wp + (size_t)(cs * 4 + i) * DKDIM + chunk * 16);
      float4 wa = w4[0], wb = w4[1], wc = w4[2], wd = w4[3];
      float xi = xc[i];
      acc[0]  = fmaf(xi, wa.x, acc[0]);  acc[1]  = fmaf(xi, wa.y, acc[1]);
      acc[2]  = fmaf(xi, wa.z, acc[2]);  acc[3]  = fmaf(xi, wa.w, acc[3]);
      acc[4]  = fmaf(xi, wb.x, acc[4]);  acc[5]  = fmaf(xi, wb.y, acc[5]);
      acc[6]  = fmaf(xi, wb.z, acc[6]);  acc[7]  = fmaf(xi, wb.w, acc[7]);
      acc[8]  = fmaf(xi, wc.x, acc[8]);  acc[9]  = fmaf(xi, wc.y, acc[9]);
      acc[10] = fmaf(xi, wc.z, acc[10]); acc[11] = fmaf(xi, wc.w, acc[11]);
      acc[12] = fmaf(xi, wd.x, acc[12]); acc[13] = fmaf(xi, wd.y, acc[13]);
      acc[14] = fmaf(xi, wd.z, acc[14]); acc[15] = fmaf(xi, wd.w, acc[15]);
    }
  }

  const int gr = rb * 64 + lane;  // global row
  float* Of = (proj ? Kt : Qt) + (size_t)gr * 64 + chunk * 16;
  #pragma unroll
  for (int i = 0; i < 4; ++i) {
    float4 o = {acc[4 * i], acc[4 * i + 1], acc[4 * i + 2], acc[4 * i + 3]};
    ((float4*)Of)[i] = o;
  }
  unsigned short* Oh = (proj ? Kh : Qh) + (size_t)gr * 64 + chunk * 16;
  unsigned hp[8];
  #pragma unroll
  for (int i = 0; i < 8; ++i)
    hp[i] = (unsigned)f2bf(acc[2 * i]) | ((unsigned)f2bf(acc[2 * i + 1]) << 16);
  uint4 h0 = {hp[0], hp[1], hp[2], hp[3]};
  uint4 h1 = {hp[4], hp[5], hp[6], hp[7]};
  ((uint4*)Oh)[0] = h0;
  ((uint4*)Oh)[1] = h1;
}

// ---------------- Kernel 2: FUSED S + top-k + exact recompute + softmax -----
// Block = 16 rows x 4096 cols, 4 waves (wave wu owns cols wu*1024..+1023).
// Grid = 1024 blocks = 4 blocks/CU (36 KB LDS) = 16 waves/CU.
// Phase 1: MFMA tiles + register scan8r -> per-stream top-8 -> swizzled LDS
//          (512 keys/row). Phase 2: 8 lanes/row scan 64 keys -> 64 cand/row.
// Phase 3: exact fp32 recompute (same fma order), shuffle top-8, softmax.
// Phase 4: pure NT zero-fill (no patch arithmetic), s_waitcnt vmcnt(0),
//          then 8 sparse patch stores/row by the SAME wave that filled it
//          (per-wave store ordering via the waitcnt). No global load after
//          any global store -> no vmcnt entanglement.
__global__ __launch_bounds__(256, 4) void s_fused(
    const unsigned short* __restrict__ Qh, const unsigned short* __restrict__ Kh,
    const float* __restrict__ Qt, const float* __restrict__ Kt,
    float* __restrict__ out) {
  __shared__ unsigned keys[16 * 512];   // 32 KB, XOR-swizzled
  __shared__ unsigned cand[16][64];     // 4 KB
  float (*pval)[8] = (float(*)[8])keys;          // overlay (keys dead after ph2)
  int   (*pcol)[8] = (int(*)[8])(keys + 128);

  const int t = threadIdx.x;
  const int lane = t & 63;
  const int wu = __builtin_amdgcn_readfirstlane(t >> 6);
  // XCD-chunked bijective swizzle (1024 = 8*128): each XCD gets 128
  // consecutive row-blocks -> per-XCD K working set = 1 batch (L2-resident).
  const int bid = blockIdx.x;
  const int orig = (bid & 7) * 128 + (bid >> 3);
  const int blockrow = orig * 16;  // global row base
  const int b = blockrow >> 12;    // batch

  const int l15 = lane & 15, lk = lane >> 4;
  // A-fragments: the block's 16 Q rows. row = lane&15, k = (lane>>4)*8+j.
  const int rowg = blockrow + l15;
  const short8v a0 = *(const short8v*)(Qh + (size_t)rowg * 64 + lk * 8);
  const short8v a1 = *(const short8v*)(Qh + (size_t)rowg * 64 + lk * 8 + 32);
  const unsigned short* Kb = Kh + ((size_t)(b << 12)) * 64;

  // ---- Phase 1: MFMA + register scan over my 1024-col slice ----
  unsigned tk[4][8]; unsigned tmin[4]; int tmpos[4];
  #pragma unroll 1
  for (int g = 0; g < 8; ++g) {    // 8 groups of 8 col-tiles
    unsigned kv[4][8];
    #pragma unroll
    for (int t8 = 0; t8 < 8; ++t8) {
      const int col = wu * 1024 + (g * 8 + t8) * 16 + l15;
      const unsigned short* kp = Kb + (size_t)col * 64 + lk * 8;
      const short8v b0 = *(const short8v*)(kp);        // B: col=lane&15, k-half 0
      const short8v b1 = *(const short8v*)(kp + 32);   // k-half 1
      f32x4 acc = {0.f, 0.f, 0.f, 0.f};
      acc = __builtin_amdgcn_mfma_f32_16x16x32_bf16(a0, b0, acc, 0, 0, 0);
      acc = __builtin_amdgcn_mfma_f32_16x16x32_bf16(a1, b1, acc, 0, 0, 0);
      // C/D: col=lane&15, row=(lane>>4)*4+i (m89-verified). Pack to keys.
      #pragma unroll
      for (int i = 0; i < 4; ++i)
        kv[i][t8] = (mono(acc[i]) & 0xFFFFF000u) | (unsigned)col;
    }
    if (g == 0) {
      #pragma unroll
      for (int i = 0; i < 4; ++i) seed8r(kv[i], tk[i], tmin[i], tmpos[i]);
    } else {
      #pragma unroll
      for (int i = 0; i < 4; ++i) scan8r(kv[i], tk[i], tmin[i], tmpos[i]);
    }
  }
  // write per-stream top-8: row = lk*4+i, off = wu*128 + l15*8 (swizzled)
  #pragma unroll
  for (int i = 0; i < 4; ++i) {
    const int row = lk * 4 + i;
    const int off = wu * 128 + l15 * 8;
    uint4 s0 = {tk[i][0], tk[i][1], tk[i][2], tk[i][3]};
    uint4 s1 = {tk[i][4], tk[i][5], tk[i][6], tk[i][7]};
    *(uint4*)&keys[kswz(row, off)] = s0;
    *(uint4*)&keys[kswz(row, off + 4)] = s1;
  }
  __syncthreads();

  // ---- Phase 2: 8 scan-lanes/row, each scans a 64-key span -> 64 cand/row --
  if ((t & 15) < 8) {
    const int row = t >> 4, s = t & 7;
    const int base = s * 64;
    unsigned kv[8]; unsigned mt[8]; unsigned mmin; int mmpos;
    ld8swz(keys, row, base, kv);
    seed8r(kv, mt, mmin, mmpos);
    #pragma unroll
    for (int m = 1; m < 8; ++m) {
      ld8swz(keys, row, base + m * 8, kv);
      scan8r(kv, mt, mmin, mmpos);
    }
    uint4 o0 = {mt[0], mt[1], mt[2], mt[3]};
    uint4 o1 = {mt[4], mt[5], mt[6], mt[7]};
    uint4* cp = (uint4*)(&cand[row][s * 8]);
    cp[0] = o0; cp[1] = o1;
  }
  __syncthreads();

  // ---- Phase 3: exact fp32 recompute of 64 candidates, top-8, softmax -----
  #pragma unroll 1
  for (int p = 0; p < 4; ++p) {
    const int rr = p * 4 + wu;     // my wave's row this pass
    const unsigned key = cand[rr][lane];
    const int col = (int)(key & 0xFFFu);
    const float4* Kp = (const float4*)(Kt + ((size_t)((b << 12) + col)) * 64);
    const float4* Qp = (const float4*)(Qt + (size_t)(blockrow + rr) * 64);  // uniform
    float s = 0.f;
    #pragma unroll
    for (int g2 = 0; g2 < 16; ++g2) {
      float4 qf = Qp[g2];
      float4 kf = Kp[g2];
      s = fmaf(qf.x, kf.x, s);
      s = fmaf(qf.y, kf.y, s);
      s = fmaf(qf.z, kf.z, s);
      s = fmaf(qf.w, kf.w, s);
    }
    unsigned kx = mono(s);  // full precision: exact ordering
    float vals[8]; int cols[8];
    #pragma unroll
    for (int it = 0; it < 8; ++it) {
      unsigned m = kx;
      #pragma unroll
      for (int d = 1; d < 64; d <<= 1) m = umaxu(m, (unsigned)__shfl_xor((int)m, d, 64));
      unsigned long long win = __ballot(kx == m);
      int wl = (int)__ffsll(win) - 1;
      cols[it] = __shfl(col, wl, 64);
      vals[it] = unmono(m);
      if (lane == wl) kx = 0u;   // exclude winner
    }
    float vq[8]; float sum = 0.f;
    #pragma unroll
    for (int it = 0; it < 8; ++it) { vq[it] = __expf((vals[it] - vals[0]) * SCALE); sum += vq[it]; }
    float inv = 1.f / sum;
    if (lane < 8) {
      pval[rr][lane] = vq[lane] * inv;
      pcol[rr][lane] = cols[lane];
    }
  }
  __syncthreads();

  // ---- Phase 4a: pure NT zero-fill; wave wu fills rows wu*4..+3 ----
  {
    const v4f z = {0.f, 0.f, 0.f, 0.f};
    #pragma unroll 1
    for (int j = 0; j < 4; ++j) {
      const int sr = wu * 4 + j;
      v4f* orow4 = (v4f*)(out + ((size_t)(blockrow + sr) << 12));
      #pragma unroll
      for (int i = 0; i < 16; ++i)
        __builtin_nontemporal_store(z, &orow4[(size_t)i * 64 + lane]);
    }
  }
  // drain fill stores (per-wave) so the sparse patch below lands after them
  asm volatile("s_waitcnt vmcnt(0)" ::: "memory");
  // ---- Phase 4b: sparse patch: same wave that filled the row scatters it --
  if (lane < 32) {
    const int sr = wu * 4 + (lane >> 3);
    const int q = lane & 7;
    out[((size_t)(blockrow + sr) << 12) + (size_t)pcol[sr][q]] = pval[sr][q];
  }
}

extern "C" void kernel_launch(void* const* d_in, const int* in_sizes, int n_in,
                              void* d_out, int out_size, void* d_ws, size_t ws_size,
                              hipStream_t stream) {
  const float* x  = (const float*)d_in[0];
  const float* Wq = (const float*)d_in[1];
  const float* Wk = (const float*)d_in[2];
  float* out = (float*)d_out;

  char* ws = (char*)d_ws;                       // 12 MB used
  float* Qt = (float*)ws;                       // 4 MB fp32 [row][64]
  float* Kt = (float*)(ws + ((size_t)4 << 20)); // 4 MB
  unsigned short* Qh = (unsigned short*)(ws + ((size_t)8 << 20));   // 2 MB bf16
  unsigned short* Kh = (unsigned short*)(ws + ((size_t)10 << 20));  // 2 MB

  qk_proj<<<dim3(NROW / 64), 512, 0, stream>>>(x, Wq, Wk, Qt, Kt, Qh, Kh);
  s_fused<<<1024, 256, 0, stream>>>(Qh, Kh, Qt, Kt, out);
}